// Round 1
// baseline (771.669 us; speedup 1.0000x reference)
//
#include <hip/hip_runtime.h>
#include <math.h>

#define B_IMG   2
#define N_PROP  2000
#define N_GT    16
#define NPROPS  2016        // N_PROP + N_GT
#define C_FEAT  256
#define H_FEAT  128
#define W_FEAT  128
#define HWF     (H_FEAT*W_FEAT)
#define POOL    7
#define BPI     512
#define NPOSMAX 128
#define NSEL    (B_IMG*BPI)     // 1024
#define K1      (C_FEAT*POOL*POOL)  // 12544
#define HID     1024
#define NHEAD   14              // 2 logits + 12 reg

// ---------------------------------------------------------------- threefry
__device__ __forceinline__ void threefry2x32(unsigned k0, unsigned k1,
                                             unsigned& x0, unsigned& x1) {
  unsigned ks[3] = {k0, k1, k0 ^ k1 ^ 0x1BD11BDAu};
  const int R0[4] = {13, 15, 26, 6};
  const int R1[4] = {17, 29, 16, 24};
  x0 += ks[0]; x1 += ks[1];
#pragma unroll
  for (int g = 0; g < 5; g++) {
    const int* rot = (g & 1) ? R1 : R0;
#pragma unroll
    for (int r = 0; r < 4; r++) {
      x0 += x1;
      x1 = (x1 << rot[r]) | (x1 >> (32 - rot[r]));
      x1 ^= x0;
    }
    x0 += ks[(g + 1) % 3];
    x1 += ks[(g + 2) % 3] + (unsigned)(g + 1);
  }
}

// jax_threefry_partitionable=True scheme: element j gets counter (0, j),
// bits = out0 ^ out1; uniform = bitcast((bits>>9)|0x3F800000) - 1
__global__ void k_rand(float* __restrict__ rnd) {
  int j = blockIdx.x * blockDim.x + threadIdx.x;
  if (j >= B_IMG * NPROPS) return;
  unsigned x0 = 0u, x1 = (unsigned)j;
  threefry2x32(0u, 42u, x0, x1);
  unsigned bits = x0 ^ x1;
  rnd[j] = __uint_as_float((bits >> 9) | 0x3F800000u) - 1.0f;
}

// ---------------------------------------------------------------- matching
__global__ void k_match(const float* __restrict__ proposals,
                        const float* __restrict__ gt_boxes,
                        const int* __restrict__ gt_labels,
                        int* __restrict__ matches, int* __restrict__ plab) {
  int idx = blockIdx.x * blockDim.x + threadIdx.x;
  if (idx >= B_IMG * NPROPS) return;
  int b = idx / NPROPS, i = idx - b * NPROPS;
  float p0, p1, p2, p3;
  if (i < N_PROP) {
    const float* p = proposals + ((size_t)b * N_PROP + i) * 4;
    p0 = p[0]; p1 = p[1]; p2 = p[2]; p3 = p[3];
  } else {
    const float* p = gt_boxes + ((size_t)b * N_GT + (i - N_PROP)) * 4;
    p0 = p[0]; p1 = p[1]; p2 = p[2]; p3 = p[3];
  }
  float a2 = (p2 - p0) * (p3 - p1);
  float best = -1.0f; int bg = 0;
  for (int g = 0; g < N_GT; g++) {
    const float* gb = gt_boxes + ((size_t)b * N_GT + g) * 4;
    float g0 = gb[0], g1 = gb[1], g2 = gb[2], g3 = gb[3];
    float a1 = (g2 - g0) * (g3 - g1);
    float wx = fminf(g2, p2) - fmaxf(g0, p0);
    float wy = fminf(g3, p3) - fmaxf(g1, p1);
    wx = fmaxf(wx, 0.0f); wy = fmaxf(wy, 0.0f);
    float inter = wx * wy;
    float iou = inter / (a1 + a2 - inter);
    if (iou > best) { best = iou; bg = g; }   // first-max => strict >
  }
  matches[idx] = bg;
  plab[idx] = (best < 0.5f) ? 0 : gt_labels[b * N_GT + bg];
}

// ---------------------------------------------------------------- priorities
__global__ __launch_bounds__(256) void k_prio(const float* __restrict__ rnd,
                                              const int* __restrict__ plab,
                                              float* __restrict__ prio) {
  __shared__ float rs[B_IMG * NPROPS];
  __shared__ short ls[B_IMG * NPROPS];
  int tid = threadIdx.x;
  for (int t = tid; t < B_IMG * NPROPS; t += 256) {
    rs[t] = rnd[t]; ls[t] = (short)plab[t];
  }
  __syncthreads();
  int idx = blockIdx.x * 256 + tid;
  if (idx >= B_IMG * NPROPS) return;
  int b = idx / NPROPS, i = idx - b * NPROPS;
  int base = b * NPROPS;
  float ri = rs[idx];
  float pr;
  if (ls[idx] > 0) {
    int cnt = 0;
    for (int j = 0; j < NPROPS; j++) {
      if (ls[base + j] > 0) {
        float rj = rs[base + j];
        if (rj > ri || (rj == ri && j < i)) cnt++;
      }
    }
    pr = (cnt < NPOSMAX) ? (ri + 2.0f) : -1000000000.0f;
  } else {
    pr = ri;  // negative
  }
  prio[idx] = pr;
}

// ------------------------------------------------- select + gather + encode
__global__ __launch_bounds__(256) void k_select(const float* __restrict__ prio,
    const float* __restrict__ proposals, const float* __restrict__ gt_boxes,
    const int* __restrict__ matches, const int* __restrict__ plab,
    const float* __restrict__ gt_ell,
    float* __restrict__ sel_boxes, int* __restrict__ sel_labels,
    float* __restrict__ targets) {
  __shared__ float ps[B_IMG * NPROPS];
  int tid = threadIdx.x;
  for (int t = tid; t < B_IMG * NPROPS; t += 256) ps[t] = prio[t];
  __syncthreads();
  int idx = blockIdx.x * 256 + tid;
  if (idx >= B_IMG * NPROPS) return;
  int b = idx / NPROPS, i = idx - b * NPROPS;
  int base = b * NPROPS;
  float pi = ps[idx];
  int rank = 0;
  for (int j = 0; j < NPROPS; j++) {
    float pj = ps[base + j];
    if (pj > pi || (pj == pi && j < i)) rank++;
  }
  if (rank >= BPI) return;
  int slot = b * BPI + rank;   // rank is a bijection -> unique slot (= top_k order)
  float p0, p1, p2, p3;
  if (i < N_PROP) {
    const float* p = proposals + ((size_t)b * N_PROP + i) * 4;
    p0 = p[0]; p1 = p[1]; p2 = p[2]; p3 = p[3];
  } else {
    const float* p = gt_boxes + ((size_t)b * N_GT + (i - N_PROP)) * 4;
    p0 = p[0]; p1 = p[1]; p2 = p[2]; p3 = p[3];
  }
  sel_boxes[slot * 4 + 0] = p0;
  sel_boxes[slot * 4 + 1] = p1;
  sel_boxes[slot * 4 + 2] = p2;
  sel_boxes[slot * 4 + 3] = p3;
  int lb = plab[idx];
  sel_labels[slot] = lb;
  int m = matches[idx];
  const float* e = gt_ell + ((size_t)b * N_GT + m) * 5;
  float ea = e[0], eb = e[1], ex = e[2], ey = e[3], eth = e[4];
  float w = fmaxf(p2 - p0, 1.0f), h = fmaxf(p3 - p1, 1.0f);
  float cx = 0.5f * (p0 + p2), cy = 0.5f * (p1 + p3);
  float* t = targets + (size_t)slot * 6;
  t[0] = (ex - cx) / w;
  t[1] = (ey - cy) / h;
  t[2] = logf(fmaxf(2.0f * ea, 0.001f) / w);
  t[3] = logf(fmaxf(2.0f * eb, 0.001f) / h);
  t[4] = sinf(2.0f * eth);
  t[5] = cosf(2.0f * eth);
}

// ------------------------------------------------------------- NCHW -> NHWC
__global__ __launch_bounds__(256) void k_transpose(const float* __restrict__ in,
                                                   float* __restrict__ out) {
  __shared__ float tile[32][33];
  int b = blockIdx.z;
  int s0 = blockIdx.x * 32;   // hw
  int c0 = blockIdx.y * 32;   // channel
  int tx = threadIdx.x, ty = threadIdx.y;
  const float* src = in + (size_t)b * C_FEAT * HWF;
  float* dst = out + (size_t)b * HWF * C_FEAT;
#pragma unroll
  for (int yy = ty; yy < 32; yy += 8)
    tile[yy][tx] = src[(size_t)(c0 + yy) * HWF + s0 + tx];
  __syncthreads();
#pragma unroll
  for (int yy = ty; yy < 32; yy += 8)
    dst[(size_t)(s0 + yy) * C_FEAT + c0 + tx] = tile[tx][yy];
}

// ---------------------------------------------------------------- roi align
// block: 256 threads = channels; grid (NSEL, 7=py). X[n][(py*7+px)*256 + c]
__global__ __launch_bounds__(256) void k_roialign(const float* __restrict__ featT,
                                                  const float* __restrict__ sel_boxes,
                                                  float* __restrict__ X) {
  int n = blockIdx.x;
  int py = blockIdx.y;
  int c = threadIdx.x;
  int b = n >> 9;  // /BPI
  const float* bx = sel_boxes + (size_t)n * 4;
  float x1 = bx[0] * 0.125f, y1 = bx[1] * 0.125f;
  float x2 = bx[2] * 0.125f, y2 = bx[3] * 0.125f;
  float bw = fmaxf(x2 - x1, 1.0f) / 7.0f;
  float bh = fmaxf(y2 - y1, 1.0f) / 7.0f;
  const float* base = featT + (size_t)b * HWF * C_FEAT;
  int y0A[2]; float lyA[2];
#pragma unroll
  for (int sy = 0; sy < 2; sy++) {
    float off = ((float)(py * 2 + sy) + 0.5f) * 0.5f;
    float ys = fminf(fmaxf(y1 + off * bh, 0.0f), 127.0f);
    int y0 = (int)fminf(fmaxf(floorf(ys), 0.0f), 126.0f);
    y0A[sy] = y0; lyA[sy] = ys - (float)y0;
  }
  for (int px = 0; px < 7; px++) {
    float acc = 0.0f;
#pragma unroll
    for (int sx = 0; sx < 2; sx++) {
      float off = ((float)(px * 2 + sx) + 0.5f) * 0.5f;
      float xs = fminf(fmaxf(x1 + off * bw, 0.0f), 127.0f);
      int x0 = (int)fminf(fmaxf(floorf(xs), 0.0f), 126.0f);
      float lx = xs - (float)x0;
#pragma unroll
      for (int sy = 0; sy < 2; sy++) {
        int y0 = y0A[sy]; float ly = lyA[sy];
        const float* p = base + ((size_t)(y0 * W_FEAT + x0)) * C_FEAT + c;
        float v00 = p[0];
        float v01 = p[C_FEAT];
        float v10 = p[W_FEAT * C_FEAT];
        float v11 = p[W_FEAT * C_FEAT + C_FEAT];
        float wy1 = ly, wy0 = 1.0f - ly, wx1 = lx, wx0 = 1.0f - lx;
        acc += v00 * (wy0 * wx0) + v01 * (wy0 * wx1) + v10 * (wy1 * wx0) + v11 * (wy1 * wx1);
      }
    }
    X[(size_t)n * K1 + (size_t)(py * 7 + px) * C_FEAT + c] = acc * 0.25f;
  }
}

// ------------------------------------------------------- split-K fp32 GEMM
// C[m][n] partial over K-chunk. A: 1024 x K row-major. B: w row-major K x 1024
// PERM=1: logical k = p*256+c maps to w1 row c*49+p (pooled layout (p,c)).
template <int PERM>
__global__ __launch_bounds__(256) void k_sgemm(const float* __restrict__ A,
                                               const float* __restrict__ Bm,
                                               float* __restrict__ P,
                                               int K, int KC) {
  __shared__ float As[16][64];
  __shared__ float Bs[16][64];
  int tid = threadIdx.x;
  int n0 = blockIdx.x * 64, m0 = blockIdx.y * 64;
  int kz = blockIdx.z;
  int kbeg = kz * KC;
  int arow = tid >> 2, ak4 = (tid & 3) << 2;
  int bkrow = tid >> 4, bn4 = (tid & 15) << 2;
  int mi = (tid >> 4) << 2, ni = (tid & 15) << 2;
  float acc[4][4] = {{0.0f}};
  for (int k0 = kbeg; k0 < kbeg + KC; k0 += 16) {
    float4 av = *(const float4*)(A + (size_t)(m0 + arow) * K + k0 + ak4);
    int gk = k0 + bkrow;
    int brow = PERM ? ((gk & 255) * 49 + (gk >> 8)) : gk;
    float4 bv = *(const float4*)(Bm + (size_t)brow * HID + n0 + bn4);
    __syncthreads();
    As[ak4 + 0][arow] = av.x;
    As[ak4 + 1][arow] = av.y;
    As[ak4 + 2][arow] = av.z;
    As[ak4 + 3][arow] = av.w;
    *(float4*)&Bs[bkrow][bn4] = bv;
    __syncthreads();
#pragma unroll
    for (int kk = 0; kk < 16; kk++) {
      float aa[4], bb[4];
#pragma unroll
      for (int x = 0; x < 4; x++) { aa[x] = As[kk][mi + x]; bb[x] = Bs[kk][ni + x]; }
#pragma unroll
      for (int ii = 0; ii < 4; ii++)
#pragma unroll
        for (int jj = 0; jj < 4; jj++)
          acc[ii][jj] = fmaf(aa[ii], bb[jj], acc[ii][jj]);
    }
  }
#pragma unroll
  for (int ii = 0; ii < 4; ii++) {
    float4 o = make_float4(acc[ii][0], acc[ii][1], acc[ii][2], acc[ii][3]);
    *(float4*)(P + (size_t)kz * HID * HID + (size_t)(m0 + mi + ii) * HID + n0 + ni) = o;
  }
}

// reduce split-K partials + bias + relu
__global__ __launch_bounds__(256) void k_reduce_relu(const float* __restrict__ P,
                                                     const float* __restrict__ bias,
                                                     float* __restrict__ O) {
  int idx4 = blockIdx.x * 256 + threadIdx.x;  // one float4 per thread
  int m = idx4 >> 8;
  int n4 = (idx4 & 255) << 2;
  float4 s = *(const float4*)(bias + n4);
#pragma unroll
  for (int z = 0; z < 4; z++) {
    float4 p = *(const float4*)(P + ((size_t)z << 20) + ((size_t)m << 10) + n4);
    s.x += p.x; s.y += p.y; s.z += p.z; s.w += p.w;
  }
  float4 o = make_float4(fmaxf(s.x, 0.0f), fmaxf(s.y, 0.0f),
                         fmaxf(s.z, 0.0f), fmaxf(s.w, 0.0f));
  *(float4*)(O + ((size_t)m << 10) + n4) = o;
}

// --------------------------------------------------------------- head GEMM
// Y[row][j] = H2[row] . Wcat[:,j] + bcat[j]; j<2 -> wc/bc, else wr/br
__global__ __launch_bounds__(256) void k_head(const float* __restrict__ H2,
                                              const float* __restrict__ wc,
                                              const float* __restrict__ bc,
                                              const float* __restrict__ wr,
                                              const float* __restrict__ br,
                                              float* __restrict__ Y) {
  __shared__ float Wl[HID * NHEAD];
  int tid = threadIdx.x;
  for (int t = tid; t < HID * NHEAD; t += 256) {
    int k = t / NHEAD, j = t - k * NHEAD;
    Wl[t] = (j < 2) ? wc[k * 2 + j] : wr[k * 12 + (j - 2)];
  }
  __syncthreads();
  int wave = tid >> 6, lane = tid & 63;
  int row = blockIdx.x * 4 + wave;
  float acc[NHEAD];
#pragma unroll
  for (int j = 0; j < NHEAD; j++) acc[j] = 0.0f;
  const float* h = H2 + (size_t)row * HID;
  for (int k = lane; k < HID; k += 64) {
    float hv = h[k];
    const float* wrow = &Wl[k * NHEAD];
#pragma unroll
    for (int j = 0; j < NHEAD; j++) acc[j] = fmaf(hv, wrow[j], acc[j]);
  }
#pragma unroll
  for (int j = 0; j < NHEAD; j++) {
    float v = acc[j];
    for (int off = 32; off > 0; off >>= 1) v += __shfl_down(v, off);
    if (lane == 0) Y[(size_t)row * NHEAD + j] = v + ((j < 2) ? bc[j] : br[j - 2]);
  }
}

// ------------------------------------------------------------------- losses
__global__ __launch_bounds__(1024) void k_loss(const float* __restrict__ Y,
                                               const int* __restrict__ sel_labels,
                                               const float* __restrict__ T,
                                               float* __restrict__ out) {
  __shared__ float sc[1024];
  __shared__ float sr[1024];
  int n = threadIdx.x;
  float l0 = Y[(size_t)n * NHEAD + 0], l1 = Y[(size_t)n * NHEAD + 1];
  int lb = sel_labels[n];
  float mx = fmaxf(l0, l1);
  float lse = mx + logf(expf(l0 - mx) + expf(l1 - mx));
  float ce = lse - (lb ? l1 : l0);
  float reg = 0.0f;
  if (lb > 0) {
    const float beta = 1.0f / 9.0f;
    const float* pr = Y + (size_t)n * NHEAD + 2 + lb * 6;
    const float* t = T + (size_t)n * 6;
#pragma unroll
    for (int j = 0; j < 6; j++) {
      float d = fabsf(pr[j] - t[j]);
      reg += (d < beta) ? (0.5f * d * d / beta) : (d - 0.5f * beta);
    }
  }
  sc[n] = ce; sr[n] = reg;
  __syncthreads();
  for (int s = 512; s > 0; s >>= 1) {
    if (n < s) { sc[n] += sc[n + s]; sr[n] += sr[n + s]; }
    __syncthreads();
  }
  if (n == 0) {
    out[0] = sc[0] * (1.0f / 1024.0f);
    out[1] = sr[0] * (1.0f / 1024.0f);
  }
}

// ------------------------------------------------------------------ launch
extern "C" void kernel_launch(void* const* d_in, const int* in_sizes, int n_in,
                              void* d_out, int out_size, void* d_ws, size_t ws_size,
                              hipStream_t stream) {
  const float* features  = (const float*)d_in[0];
  const float* proposals = (const float*)d_in[1];
  const float* gt_boxes  = (const float*)d_in[2];
  const int*   gt_labels = (const int*)d_in[3];
  const float* gt_ell    = (const float*)d_in[4];
  const float* w1 = (const float*)d_in[5];
  const float* b1 = (const float*)d_in[6];
  const float* w2 = (const float*)d_in[7];
  const float* b2 = (const float*)d_in[8];
  const float* wc = (const float*)d_in[9];
  const float* bc = (const float*)d_in[10];
  const float* wr = (const float*)d_in[11];
  const float* br = (const float*)d_in[12];
  float* out = (float*)d_out;

  char* ws = (char*)d_ws;
  size_t off = 0;
  auto take = [&](size_t bytes) -> void* {
    void* p = ws + off;
    off = (off + bytes + 255) & ~(size_t)255;
    return p;
  };
  float* featT     = (float*)take((size_t)B_IMG * HWF * C_FEAT * 4);   // 33.5 MB
  float* X         = (float*)take((size_t)NSEL * K1 * 4);              // 51.4 MB
  float* P         = (float*)take((size_t)4 * HID * HID * 4);          // 16.8 MB
  float* H1s       = (float*)take((size_t)NSEL * HID * 4);             // 4.2 MB
  float* H2s       = (float*)take((size_t)NSEL * HID * 4);             // 4.2 MB
  float* Y         = (float*)take((size_t)NSEL * NHEAD * 4);
  float* rnd       = (float*)take((size_t)B_IMG * NPROPS * 4);
  int*   matches   = (int*)take((size_t)B_IMG * NPROPS * 4);
  int*   plab      = (int*)take((size_t)B_IMG * NPROPS * 4);
  float* prio      = (float*)take((size_t)B_IMG * NPROPS * 4);
  float* sel_boxes = (float*)take((size_t)NSEL * 4 * 4);
  int*   sel_lab   = (int*)take((size_t)NSEL * 4);
  float* targets   = (float*)take((size_t)NSEL * 6 * 4);

  k_rand<<<(B_IMG * NPROPS + 255) / 256, 256, 0, stream>>>(rnd);
  k_transpose<<<dim3(HWF / 32, C_FEAT / 32, B_IMG), dim3(32, 8), 0, stream>>>(features, featT);
  k_match<<<(B_IMG * NPROPS + 255) / 256, 256, 0, stream>>>(proposals, gt_boxes, gt_labels,
                                                            matches, plab);
  k_prio<<<(B_IMG * NPROPS + 255) / 256, 256, 0, stream>>>(rnd, plab, prio);
  k_select<<<(B_IMG * NPROPS + 255) / 256, 256, 0, stream>>>(prio, proposals, gt_boxes,
                                                             matches, plab, gt_ell,
                                                             sel_boxes, sel_lab, targets);
  k_roialign<<<dim3(NSEL, POOL), 256, 0, stream>>>(featT, sel_boxes, X);

  // GEMM1: X(1024 x 12544) @ perm(w1) -> H1, split-K=4 (KC=3136)
  k_sgemm<1><<<dim3(16, 16, 4), 256, 0, stream>>>(X, w1, P, K1, K1 / 4);
  k_reduce_relu<<<(HID * HID / 4) / 256, 256, 0, stream>>>(P, b1, H1s);
  // GEMM2: H1 @ w2 -> H2, split-K=4 (KC=256)
  k_sgemm<0><<<dim3(16, 16, 4), 256, 0, stream>>>(H1s, w2, P, HID, HID / 4);
  k_reduce_relu<<<(HID * HID / 4) / 256, 256, 0, stream>>>(P, b2, H2s);

  k_head<<<NSEL / 4, 256, 0, stream>>>(H2s, wc, bc, wr, br, Y);
  k_loss<<<1, 1024, 0, stream>>>(Y, sel_lab, targets, out);
}

// Round 2
// 530.792 us; speedup vs baseline: 1.4538x; 1.4538x over previous
//
#include <hip/hip_runtime.h>
#include <hip/hip_bf16.h>
#include <math.h>

#define B_IMG   2
#define N_PROP  2000
#define N_GT    16
#define NPROPS  2016        // N_PROP + N_GT
#define C_FEAT  256
#define H_FEAT  128
#define W_FEAT  128
#define HWF     (H_FEAT*W_FEAT)
#define POOL    7
#define BPI     512
#define NPOSMAX 128
#define NSEL    (B_IMG*BPI)     // 1024
#define K1      (C_FEAT*POOL*POOL)  // 12544
#define HID     1024
#define NHEAD   14              // 2 logits + 12 reg

typedef short bf16x8f __attribute__((ext_vector_type(8)));   // 8 bf16 = 4 VGPRs
typedef float f32x4f  __attribute__((ext_vector_type(4)));
typedef short short4v __attribute__((ext_vector_type(4)));

// ---------------------------------------------------------------- threefry
__device__ __forceinline__ void threefry2x32(unsigned k0, unsigned k1,
                                             unsigned& x0, unsigned& x1) {
  unsigned ks[3] = {k0, k1, k0 ^ k1 ^ 0x1BD11BDAu};
  const int R0[4] = {13, 15, 26, 6};
  const int R1[4] = {17, 29, 16, 24};
  x0 += ks[0]; x1 += ks[1];
#pragma unroll
  for (int g = 0; g < 5; g++) {
    const int* rot = (g & 1) ? R1 : R0;
#pragma unroll
    for (int r = 0; r < 4; r++) {
      x0 += x1;
      x1 = (x1 << rot[r]) | (x1 >> (32 - rot[r]));
      x1 ^= x0;
    }
    x0 += ks[(g + 1) % 3];
    x1 += ks[(g + 2) % 3] + (unsigned)(g + 1);
  }
}

__global__ void k_rand(float* __restrict__ rnd) {
  int j = blockIdx.x * blockDim.x + threadIdx.x;
  if (j >= B_IMG * NPROPS) return;
  unsigned x0 = 0u, x1 = (unsigned)j;
  threefry2x32(0u, 42u, x0, x1);
  unsigned bits = x0 ^ x1;
  rnd[j] = __uint_as_float((bits >> 9) | 0x3F800000u) - 1.0f;
}

// ---------------------------------------------------------------- matching
__global__ void k_match(const float* __restrict__ proposals,
                        const float* __restrict__ gt_boxes,
                        const int* __restrict__ gt_labels,
                        int* __restrict__ matches, int* __restrict__ plab) {
  int idx = blockIdx.x * blockDim.x + threadIdx.x;
  if (idx >= B_IMG * NPROPS) return;
  int b = idx / NPROPS, i = idx - b * NPROPS;
  float p0, p1, p2, p3;
  if (i < N_PROP) {
    const float* p = proposals + ((size_t)b * N_PROP + i) * 4;
    p0 = p[0]; p1 = p[1]; p2 = p[2]; p3 = p[3];
  } else {
    const float* p = gt_boxes + ((size_t)b * N_GT + (i - N_PROP)) * 4;
    p0 = p[0]; p1 = p[1]; p2 = p[2]; p3 = p[3];
  }
  float a2 = (p2 - p0) * (p3 - p1);
  float best = -1.0f; int bg = 0;
  for (int g = 0; g < N_GT; g++) {
    const float* gb = gt_boxes + ((size_t)b * N_GT + g) * 4;
    float g0 = gb[0], g1 = gb[1], g2 = gb[2], g3 = gb[3];
    float a1 = (g2 - g0) * (g3 - g1);
    float wx = fminf(g2, p2) - fmaxf(g0, p0);
    float wy = fminf(g3, p3) - fmaxf(g1, p1);
    wx = fmaxf(wx, 0.0f); wy = fmaxf(wy, 0.0f);
    float inter = wx * wy;
    float iou = inter / (a1 + a2 - inter);
    if (iou > best) { best = iou; bg = g; }
  }
  matches[idx] = bg;
  plab[idx] = (best < 0.5f) ? 0 : gt_labels[b * N_GT + bg];
}

// ---------------------------------------------------------------- priorities
__global__ __launch_bounds__(256) void k_prio(const float* __restrict__ rnd,
                                              const int* __restrict__ plab,
                                              float* __restrict__ prio) {
  __shared__ float rs[B_IMG * NPROPS];
  __shared__ short ls[B_IMG * NPROPS];
  int tid = threadIdx.x;
  for (int t = tid; t < B_IMG * NPROPS; t += 256) {
    rs[t] = rnd[t]; ls[t] = (short)plab[t];
  }
  __syncthreads();
  int idx = blockIdx.x * 256 + tid;
  if (idx >= B_IMG * NPROPS) return;
  int b = idx / NPROPS, i = idx - b * NPROPS;
  int base = b * NPROPS;
  float ri = rs[idx];
  float pr;
  if (ls[idx] > 0) {
    int cnt = 0;
    for (int j = 0; j < NPROPS; j++) {
      if (ls[base + j] > 0) {
        float rj = rs[base + j];
        if (rj > ri || (rj == ri && j < i)) cnt++;
      }
    }
    pr = (cnt < NPOSMAX) ? (ri + 2.0f) : -1000000000.0f;
  } else {
    pr = ri;
  }
  prio[idx] = pr;
}

// ------------------------------------------------- select + gather + encode
__global__ __launch_bounds__(256) void k_select(const float* __restrict__ prio,
    const float* __restrict__ proposals, const float* __restrict__ gt_boxes,
    const int* __restrict__ matches, const int* __restrict__ plab,
    const float* __restrict__ gt_ell,
    float* __restrict__ sel_boxes, int* __restrict__ sel_labels,
    float* __restrict__ targets) {
  __shared__ float ps[B_IMG * NPROPS];
  int tid = threadIdx.x;
  for (int t = tid; t < B_IMG * NPROPS; t += 256) ps[t] = prio[t];
  __syncthreads();
  int idx = blockIdx.x * 256 + tid;
  if (idx >= B_IMG * NPROPS) return;
  int b = idx / NPROPS, i = idx - b * NPROPS;
  int base = b * NPROPS;
  float pi = ps[idx];
  int rank = 0;
  for (int j = 0; j < NPROPS; j++) {
    float pj = ps[base + j];
    if (pj > pi || (pj == pi && j < i)) rank++;
  }
  if (rank >= BPI) return;
  int slot = b * BPI + rank;
  float p0, p1, p2, p3;
  if (i < N_PROP) {
    const float* p = proposals + ((size_t)b * N_PROP + i) * 4;
    p0 = p[0]; p1 = p[1]; p2 = p[2]; p3 = p[3];
  } else {
    const float* p = gt_boxes + ((size_t)b * N_GT + (i - N_PROP)) * 4;
    p0 = p[0]; p1 = p[1]; p2 = p[2]; p3 = p[3];
  }
  sel_boxes[slot * 4 + 0] = p0;
  sel_boxes[slot * 4 + 1] = p1;
  sel_boxes[slot * 4 + 2] = p2;
  sel_boxes[slot * 4 + 3] = p3;
  int lb = plab[idx];
  sel_labels[slot] = lb;
  int m = matches[idx];
  const float* e = gt_ell + ((size_t)b * N_GT + m) * 5;
  float ea = e[0], eb = e[1], ex = e[2], ey = e[3], eth = e[4];
  float w = fmaxf(p2 - p0, 1.0f), h = fmaxf(p3 - p1, 1.0f);
  float cx = 0.5f * (p0 + p2), cy = 0.5f * (p1 + p3);
  float* t = targets + (size_t)slot * 6;
  t[0] = (ex - cx) / w;
  t[1] = (ey - cy) / h;
  t[2] = logf(fmaxf(2.0f * ea, 0.001f) / w);
  t[3] = logf(fmaxf(2.0f * eb, 0.001f) / h);
  t[4] = sinf(2.0f * eth);
  t[5] = cosf(2.0f * eth);
}

// ------------------------------------------------------------- NCHW -> NHWC
__global__ __launch_bounds__(256) void k_transpose(const float* __restrict__ in,
                                                   float* __restrict__ out) {
  __shared__ float tile[32][33];
  int b = blockIdx.z;
  int s0 = blockIdx.x * 32;   // hw
  int c0 = blockIdx.y * 32;   // channel
  int tx = threadIdx.x, ty = threadIdx.y;
  const float* src = in + (size_t)b * C_FEAT * HWF;
  float* dst = out + (size_t)b * HWF * C_FEAT;
#pragma unroll
  for (int yy = ty; yy < 32; yy += 8)
    tile[yy][tx] = src[(size_t)(c0 + yy) * HWF + s0 + tx];
  __syncthreads();
#pragma unroll
  for (int yy = ty; yy < 32; yy += 8)
    dst[(size_t)(s0 + yy) * C_FEAT + c0 + tx] = tile[tx][yy];
}

// ----------------------------------------- weight casts: fp32 [K][N] -> bf16 [N][K]
// PERM=1: output k-index kx = p*256+c maps to input row c*49+p (w1 / X order)
template <int PERM>
__global__ __launch_bounds__(256) void k_castT(const float* __restrict__ W,
                                               __hip_bfloat16* __restrict__ WT,
                                               int Kout) {
  __shared__ float tile[32][33];
  int c0 = blockIdx.x * 32;   // inner index tile (c for PERM, k otherwise)
  int n0 = blockIdx.y * 32;
  int tx = threadIdx.x, ty = threadIdx.y;
  int np = PERM ? 49 : 1;
  for (int p = 0; p < np; p++) {
#pragma unroll
    for (int yy = ty; yy < 32; yy += 8) {
      int krow = PERM ? ((c0 + yy) * 49 + p) : (c0 + yy);
      tile[yy][tx] = W[(size_t)krow * HID + n0 + tx];
    }
    __syncthreads();
#pragma unroll
    for (int yy = ty; yy < 32; yy += 8) {
      int kx = PERM ? (p * 256 + c0 + tx) : (c0 + tx);
      WT[(size_t)(n0 + yy) * Kout + kx] = __float2bfloat16(tile[tx][yy]);
    }
    __syncthreads();
  }
}

// ---------------------------------------------------------------- roi align
// block: 256 threads = channels; grid (NSEL, 7=py). X[n][(py*7+px)*256 + c] (bf16)
__global__ __launch_bounds__(256) void k_roialign(const float* __restrict__ featT,
                                                  const float* __restrict__ sel_boxes,
                                                  __hip_bfloat16* __restrict__ X) {
  int n = blockIdx.x;
  int py = blockIdx.y;
  int c = threadIdx.x;
  int b = n >> 9;
  const float* bx = sel_boxes + (size_t)n * 4;
  float x1 = bx[0] * 0.125f, y1 = bx[1] * 0.125f;
  float x2 = bx[2] * 0.125f, y2 = bx[3] * 0.125f;
  float bw = fmaxf(x2 - x1, 1.0f) / 7.0f;
  float bh = fmaxf(y2 - y1, 1.0f) / 7.0f;
  const float* base = featT + (size_t)b * HWF * C_FEAT;
  int y0A[2]; float lyA[2];
#pragma unroll
  for (int sy = 0; sy < 2; sy++) {
    float off = ((float)(py * 2 + sy) + 0.5f) * 0.5f;
    float ys = fminf(fmaxf(y1 + off * bh, 0.0f), 127.0f);
    int y0 = (int)fminf(fmaxf(floorf(ys), 0.0f), 126.0f);
    y0A[sy] = y0; lyA[sy] = ys - (float)y0;
  }
  for (int px = 0; px < 7; px++) {
    float acc = 0.0f;
#pragma unroll
    for (int sx = 0; sx < 2; sx++) {
      float off = ((float)(px * 2 + sx) + 0.5f) * 0.5f;
      float xs = fminf(fmaxf(x1 + off * bw, 0.0f), 127.0f);
      int x0 = (int)fminf(fmaxf(floorf(xs), 0.0f), 126.0f);
      float lx = xs - (float)x0;
#pragma unroll
      for (int sy = 0; sy < 2; sy++) {
        int y0 = y0A[sy]; float ly = lyA[sy];
        const float* p = base + ((size_t)(y0 * W_FEAT + x0)) * C_FEAT + c;
        float v00 = p[0];
        float v01 = p[C_FEAT];
        float v10 = p[W_FEAT * C_FEAT];
        float v11 = p[W_FEAT * C_FEAT + C_FEAT];
        float wy1 = ly, wy0 = 1.0f - ly, wx1 = lx, wx0 = 1.0f - lx;
        acc += v00 * (wy0 * wx0) + v01 * (wy0 * wx1) + v10 * (wy1 * wx0) + v11 * (wy1 * wx1);
      }
    }
    X[(size_t)n * K1 + (size_t)(py * 7 + px) * C_FEAT + c] = __float2bfloat16(acc * 0.25f);
  }
}

// ------------------------------------------------------- bf16 MFMA GEMM (split-K)
// A: M x K bf16 row-major. BT: N x K bf16 row-major. P[z]: 1024x1024 fp32 partials.
// 128x128 tile, BK=32, 4 waves each computing a 64x64 quadrant via 16x16x32 mfma.
__device__ __forceinline__ void gld_lds16(const __hip_bfloat16* g, __hip_bfloat16* l) {
  __builtin_amdgcn_global_load_lds(
      (const __attribute__((address_space(1))) void*)g,
      (__attribute__((address_space(3))) void*)l, 16, 0, 0);
}

__global__ __launch_bounds__(256) void k_mfma_gemm(const __hip_bfloat16* __restrict__ A,
                                                   const __hip_bfloat16* __restrict__ BT,
                                                   float* __restrict__ P,
                                                   int K, int KC) {
  __shared__ __align__(16) __hip_bfloat16 As[128 * 32];
  __shared__ __align__(16) __hip_bfloat16 Bs[128 * 32];
  int tid = threadIdx.x;
  int n0 = blockIdx.x * 128, m0 = blockIdx.y * 128;
  int kz = blockIdx.z;
  int kbeg = kz * KC;
  int srow = tid >> 2;          // 0..63
  int scol = (tid & 3) << 3;    // 0,8,16,24 (elements)
  int wave = tid >> 6, lane = tid & 63;
  int wm = (wave & 1) * 64, wn = (wave >> 1) * 64;
  int lm = lane & 15, quad = lane >> 4;
  f32x4f acc[4][4] = {};
  for (int k0 = kbeg; k0 < kbeg + KC; k0 += 32) {
    __syncthreads();
    gld_lds16(A  + (size_t)(m0 + srow) * K + k0 + scol,      &As[srow * 32 + scol]);
    gld_lds16(A  + (size_t)(m0 + 64 + srow) * K + k0 + scol, &As[(64 + srow) * 32 + scol]);
    gld_lds16(BT + (size_t)(n0 + srow) * K + k0 + scol,      &Bs[srow * 32 + scol]);
    gld_lds16(BT + (size_t)(n0 + 64 + srow) * K + k0 + scol, &Bs[(64 + srow) * 32 + scol]);
    __syncthreads();
    bf16x8f af[4], bf[4];
#pragma unroll
    for (int i = 0; i < 4; i++)
      af[i] = *(const bf16x8f*)&As[(wm + i * 16 + lm) * 32 + quad * 8];
#pragma unroll
    for (int j = 0; j < 4; j++)
      bf[j] = *(const bf16x8f*)&Bs[(wn + j * 16 + lm) * 32 + quad * 8];
#pragma unroll
    for (int i = 0; i < 4; i++)
#pragma unroll
      for (int j = 0; j < 4; j++)
        acc[i][j] = __builtin_amdgcn_mfma_f32_16x16x32_bf16(af[i], bf[j], acc[i][j], 0, 0, 0);
  }
  // C/D layout: col = lane&15, row = quad*4 + reg
#pragma unroll
  for (int i = 0; i < 4; i++)
#pragma unroll
    for (int j = 0; j < 4; j++) {
      float* base = P + ((size_t)kz << 20)
                      + (size_t)(m0 + wm + i * 16 + quad * 4) * HID
                      + (n0 + wn + j * 16 + lm);
#pragma unroll
      for (int r = 0; r < 4; r++) base[(size_t)r * HID] = acc[i][j][r];
    }
}

// reduce split-K partials + bias + relu; OUTBF16 chooses output dtype
template <int Z, int OUTBF16>
__global__ __launch_bounds__(256) void k_reduce(const float* __restrict__ P,
                                                const float* __restrict__ bias,
                                                void* __restrict__ O) {
  int idx4 = blockIdx.x * 256 + threadIdx.x;
  int m = idx4 >> 8;
  int n4 = (idx4 & 255) << 2;
  float4 s = *(const float4*)(bias + n4);
#pragma unroll
  for (int z = 0; z < Z; z++) {
    float4 p = *(const float4*)(P + ((size_t)z << 20) + ((size_t)m << 10) + n4);
    s.x += p.x; s.y += p.y; s.z += p.z; s.w += p.w;
  }
  s.x = fmaxf(s.x, 0.0f); s.y = fmaxf(s.y, 0.0f);
  s.z = fmaxf(s.z, 0.0f); s.w = fmaxf(s.w, 0.0f);
  if (OUTBF16) {
    __hip_bfloat16 t[4] = {__float2bfloat16(s.x), __float2bfloat16(s.y),
                           __float2bfloat16(s.z), __float2bfloat16(s.w)};
    *(short4v*)((__hip_bfloat16*)O + ((size_t)m << 10) + n4) = *(short4v*)t;
  } else {
    *(float4*)((float*)O + ((size_t)m << 10) + n4) = s;
  }
}

// --------------------------------------------------------------- head GEMM
__global__ __launch_bounds__(256) void k_head(const float* __restrict__ H2,
                                              const float* __restrict__ wc,
                                              const float* __restrict__ bc,
                                              const float* __restrict__ wr,
                                              const float* __restrict__ br,
                                              float* __restrict__ Y) {
  __shared__ float Wl[HID * NHEAD];
  int tid = threadIdx.x;
  for (int t = tid; t < HID * NHEAD; t += 256) {
    int k = t / NHEAD, j = t - k * NHEAD;
    Wl[t] = (j < 2) ? wc[k * 2 + j] : wr[k * 12 + (j - 2)];
  }
  __syncthreads();
  int wave = tid >> 6, lane = tid & 63;
  int row = blockIdx.x * 4 + wave;
  float acc[NHEAD];
#pragma unroll
  for (int j = 0; j < NHEAD; j++) acc[j] = 0.0f;
  const float* h = H2 + (size_t)row * HID;
  for (int k = lane; k < HID; k += 64) {
    float hv = h[k];
    const float* wrow = &Wl[k * NHEAD];
#pragma unroll
    for (int j = 0; j < NHEAD; j++) acc[j] = fmaf(hv, wrow[j], acc[j]);
  }
#pragma unroll
  for (int j = 0; j < NHEAD; j++) {
    float v = acc[j];
    for (int off = 32; off > 0; off >>= 1) v += __shfl_down(v, off);
    if (lane == 0) Y[(size_t)row * NHEAD + j] = v + ((j < 2) ? bc[j] : br[j - 2]);
  }
}

// ------------------------------------------------------------------- losses
__global__ __launch_bounds__(1024) void k_loss(const float* __restrict__ Y,
                                               const int* __restrict__ sel_labels,
                                               const float* __restrict__ T,
                                               float* __restrict__ out) {
  __shared__ float sc[1024];
  __shared__ float sr[1024];
  int n = threadIdx.x;
  float l0 = Y[(size_t)n * NHEAD + 0], l1 = Y[(size_t)n * NHEAD + 1];
  int lb = sel_labels[n];
  float mx = fmaxf(l0, l1);
  float lse = mx + logf(expf(l0 - mx) + expf(l1 - mx));
  float ce = lse - (lb ? l1 : l0);
  float reg = 0.0f;
  if (lb > 0) {
    const float beta = 1.0f / 9.0f;
    const float* pr = Y + (size_t)n * NHEAD + 2 + lb * 6;
    const float* t = T + (size_t)n * 6;
#pragma unroll
    for (int j = 0; j < 6; j++) {
      float d = fabsf(pr[j] - t[j]);
      reg += (d < beta) ? (0.5f * d * d / beta) : (d - 0.5f * beta);
    }
  }
  sc[n] = ce; sr[n] = reg;
  __syncthreads();
  for (int s = 512; s > 0; s >>= 1) {
    if (n < s) { sc[n] += sc[n + s]; sr[n] += sr[n + s]; }
    __syncthreads();
  }
  if (n == 0) {
    out[0] = sc[0] * (1.0f / 1024.0f);
    out[1] = sr[0] * (1.0f / 1024.0f);
  }
}

// ------------------------------------------------------------------ launch
extern "C" void kernel_launch(void* const* d_in, const int* in_sizes, int n_in,
                              void* d_out, int out_size, void* d_ws, size_t ws_size,
                              hipStream_t stream) {
  const float* features  = (const float*)d_in[0];
  const float* proposals = (const float*)d_in[1];
  const float* gt_boxes  = (const float*)d_in[2];
  const int*   gt_labels = (const int*)d_in[3];
  const float* gt_ell    = (const float*)d_in[4];
  const float* w1 = (const float*)d_in[5];
  const float* b1 = (const float*)d_in[6];
  const float* w2 = (const float*)d_in[7];
  const float* b2 = (const float*)d_in[8];
  const float* wc = (const float*)d_in[9];
  const float* bc = (const float*)d_in[10];
  const float* wr = (const float*)d_in[11];
  const float* br = (const float*)d_in[12];
  float* out = (float*)d_out;

  char* ws = (char*)d_ws;
  size_t off = 0;
  auto take = [&](size_t bytes) -> void* {
    void* p = ws + off;
    off = (off + bytes + 255) & ~(size_t)255;
    return p;
  };
  // featT (32 MiB, dead after roialign) aliases P (8x4 MiB split-K partials)
  float* featT = (float*)take((size_t)B_IMG * HWF * C_FEAT * 4);       // 32 MiB
  float* P     = featT;                                                // alias
  __hip_bfloat16* Xb  = (__hip_bfloat16*)take((size_t)NSEL * K1 * 2);  // 25.7 MB
  __hip_bfloat16* W1T = (__hip_bfloat16*)take((size_t)HID * K1 * 2);   // 25.7 MB
  __hip_bfloat16* W2T = (__hip_bfloat16*)take((size_t)HID * HID * 2);  // 2.1 MB
  __hip_bfloat16* H1b = (__hip_bfloat16*)take((size_t)NSEL * HID * 2); // 2.1 MB
  float* H2s       = (float*)take((size_t)NSEL * HID * 4);             // 4.2 MB
  float* Y         = (float*)take((size_t)NSEL * NHEAD * 4);
  float* rnd       = (float*)take((size_t)B_IMG * NPROPS * 4);
  int*   matches   = (int*)take((size_t)B_IMG * NPROPS * 4);
  int*   plab      = (int*)take((size_t)B_IMG * NPROPS * 4);
  float* prio      = (float*)take((size_t)B_IMG * NPROPS * 4);
  float* sel_boxes = (float*)take((size_t)NSEL * 4 * 4);
  int*   sel_lab   = (int*)take((size_t)NSEL * 4);
  float* targets   = (float*)take((size_t)NSEL * 6 * 4);

  k_rand<<<(B_IMG * NPROPS + 255) / 256, 256, 0, stream>>>(rnd);
  k_transpose<<<dim3(HWF / 32, C_FEAT / 32, B_IMG), dim3(32, 8), 0, stream>>>(features, featT);
  k_castT<1><<<dim3(8, 32), dim3(32, 8), 0, stream>>>(w1, W1T, K1);
  k_castT<0><<<dim3(32, 32), dim3(32, 8), 0, stream>>>(w2, W2T, HID);
  k_match<<<(B_IMG * NPROPS + 255) / 256, 256, 0, stream>>>(proposals, gt_boxes, gt_labels,
                                                            matches, plab);
  k_prio<<<(B_IMG * NPROPS + 255) / 256, 256, 0, stream>>>(rnd, plab, prio);
  k_select<<<(B_IMG * NPROPS + 255) / 256, 256, 0, stream>>>(prio, proposals, gt_boxes,
                                                             matches, plab, gt_ell,
                                                             sel_boxes, sel_lab, targets);
  k_roialign<<<dim3(NSEL, POOL), 256, 0, stream>>>(featT, sel_boxes, Xb);

  // GEMM1: Xb(1024 x 12544) @ W1T^T, split-K=8 (KC=1568), then reduce+relu -> H1b (bf16)
  k_mfma_gemm<<<dim3(8, 8, 8), 256, 0, stream>>>(Xb, W1T, P, K1, K1 / 8);
  k_reduce<8, 1><<<1024, 256, 0, stream>>>(P, b1, H1b);
  // GEMM2: H1b(1024x1024) @ W2T^T, split-K=4 (KC=256), reduce+relu -> H2 (fp32)
  k_mfma_gemm<<<dim3(8, 8, 4), 256, 0, stream>>>(H1b, W2T, P, HID, HID / 4);
  k_reduce<4, 0><<<1024, 256, 0, stream>>>(P, b2, H2s);

  k_head<<<NSEL / 4, 256, 0, stream>>>(H2s, wc, bc, wr, br, Y);
  k_loss<<<1, 1024, 0, stream>>>(Y, sel_lab, targets, out);
}

// Round 3
// 461.405 us; speedup vs baseline: 1.6724x; 1.1504x over previous
//
#include <hip/hip_runtime.h>
#include <hip/hip_bf16.h>
#include <math.h>

#define B_IMG   2
#define N_PROP  2000
#define N_GT    16
#define NPROPS  2016        // N_PROP + N_GT
#define C_FEAT  256
#define H_FEAT  128
#define W_FEAT  128
#define HWF     (H_FEAT*W_FEAT)
#define POOL    7
#define BPI     512
#define NPOSMAX 128
#define NSEL    (B_IMG*BPI)     // 1024
#define K1      (C_FEAT*POOL*POOL)  // 12544
#define HID     1024
#define NHEAD   14              // 2 logits + 12 reg

typedef short bf16x8f __attribute__((ext_vector_type(8)));   // 8 bf16 = 4 VGPRs
typedef float f32x4f  __attribute__((ext_vector_type(4)));
typedef short short4v __attribute__((ext_vector_type(4)));

// ---------------------------------------------------------------- threefry
__device__ __forceinline__ void threefry2x32(unsigned k0, unsigned k1,
                                             unsigned& x0, unsigned& x1) {
  unsigned ks[3] = {k0, k1, k0 ^ k1 ^ 0x1BD11BDAu};
  const int R0[4] = {13, 15, 26, 6};
  const int R1[4] = {17, 29, 16, 24};
  x0 += ks[0]; x1 += ks[1];
#pragma unroll
  for (int g = 0; g < 5; g++) {
    const int* rot = (g & 1) ? R1 : R0;
#pragma unroll
    for (int r = 0; r < 4; r++) {
      x0 += x1;
      x1 = (x1 << rot[r]) | (x1 >> (32 - rot[r]));
      x1 ^= x0;
    }
    x0 += ks[(g + 1) % 3];
    x1 += ks[(g + 2) % 3] + (unsigned)(g + 1);
  }
}

__global__ void k_rand(float* __restrict__ rnd) {
  int j = blockIdx.x * blockDim.x + threadIdx.x;
  if (j >= B_IMG * NPROPS) return;
  unsigned x0 = 0u, x1 = (unsigned)j;
  threefry2x32(0u, 42u, x0, x1);
  unsigned bits = x0 ^ x1;
  rnd[j] = __uint_as_float((bits >> 9) | 0x3F800000u) - 1.0f;
}

// ---------------------------------------------------------------- matching
__global__ void k_match(const float* __restrict__ proposals,
                        const float* __restrict__ gt_boxes,
                        const int* __restrict__ gt_labels,
                        int* __restrict__ matches, int* __restrict__ plab) {
  int idx = blockIdx.x * blockDim.x + threadIdx.x;
  if (idx >= B_IMG * NPROPS) return;
  int b = idx / NPROPS, i = idx - b * NPROPS;
  float p0, p1, p2, p3;
  if (i < N_PROP) {
    const float* p = proposals + ((size_t)b * N_PROP + i) * 4;
    p0 = p[0]; p1 = p[1]; p2 = p[2]; p3 = p[3];
  } else {
    const float* p = gt_boxes + ((size_t)b * N_GT + (i - N_PROP)) * 4;
    p0 = p[0]; p1 = p[1]; p2 = p[2]; p3 = p[3];
  }
  float a2 = (p2 - p0) * (p3 - p1);
  float best = -1.0f; int bg = 0;
  for (int g = 0; g < N_GT; g++) {
    const float* gb = gt_boxes + ((size_t)b * N_GT + g) * 4;
    float g0 = gb[0], g1 = gb[1], g2 = gb[2], g3 = gb[3];
    float a1 = (g2 - g0) * (g3 - g1);
    float wx = fminf(g2, p2) - fmaxf(g0, p0);
    float wy = fminf(g3, p3) - fmaxf(g1, p1);
    wx = fmaxf(wx, 0.0f); wy = fmaxf(wy, 0.0f);
    float inter = wx * wy;
    float iou = inter / (a1 + a2 - inter);
    if (iou > best) { best = iou; bg = g; }
  }
  matches[idx] = bg;
  plab[idx] = (best < 0.5f) ? 0 : gt_labels[b * N_GT + bg];
}

// ---------------------------------------------------------------- priorities
__global__ __launch_bounds__(256) void k_prio(const float* __restrict__ rnd,
                                              const int* __restrict__ plab,
                                              float* __restrict__ prio) {
  __shared__ float rs[B_IMG * NPROPS];
  __shared__ short ls[B_IMG * NPROPS];
  int tid = threadIdx.x;
  for (int t = tid; t < B_IMG * NPROPS; t += 256) {
    rs[t] = rnd[t]; ls[t] = (short)plab[t];
  }
  __syncthreads();
  int idx = blockIdx.x * 256 + tid;
  if (idx >= B_IMG * NPROPS) return;
  int b = idx / NPROPS, i = idx - b * NPROPS;
  int base = b * NPROPS;
  float ri = rs[idx];
  float pr;
  if (ls[idx] > 0) {
    int cnt = 0;
    for (int j = 0; j < NPROPS; j++) {
      if (ls[base + j] > 0) {
        float rj = rs[base + j];
        if (rj > ri || (rj == ri && j < i)) cnt++;
      }
    }
    pr = (cnt < NPOSMAX) ? (ri + 2.0f) : -1000000000.0f;
  } else {
    pr = ri;
  }
  prio[idx] = pr;
}

// ------------------------------------------------- select + gather + encode
__global__ __launch_bounds__(256) void k_select(const float* __restrict__ prio,
    const float* __restrict__ proposals, const float* __restrict__ gt_boxes,
    const int* __restrict__ matches, const int* __restrict__ plab,
    const float* __restrict__ gt_ell,
    float* __restrict__ sel_boxes, int* __restrict__ sel_labels,
    float* __restrict__ targets) {
  __shared__ float ps[B_IMG * NPROPS];
  int tid = threadIdx.x;
  for (int t = tid; t < B_IMG * NPROPS; t += 256) ps[t] = prio[t];
  __syncthreads();
  int idx = blockIdx.x * 256 + tid;
  if (idx >= B_IMG * NPROPS) return;
  int b = idx / NPROPS, i = idx - b * NPROPS;
  int base = b * NPROPS;
  float pi = ps[idx];
  int rank = 0;
  for (int j = 0; j < NPROPS; j++) {
    float pj = ps[base + j];
    if (pj > pi || (pj == pi && j < i)) rank++;
  }
  if (rank >= BPI) return;
  int slot = b * BPI + rank;
  float p0, p1, p2, p3;
  if (i < N_PROP) {
    const float* p = proposals + ((size_t)b * N_PROP + i) * 4;
    p0 = p[0]; p1 = p[1]; p2 = p[2]; p3 = p[3];
  } else {
    const float* p = gt_boxes + ((size_t)b * N_GT + (i - N_PROP)) * 4;
    p0 = p[0]; p1 = p[1]; p2 = p[2]; p3 = p[3];
  }
  sel_boxes[slot * 4 + 0] = p0;
  sel_boxes[slot * 4 + 1] = p1;
  sel_boxes[slot * 4 + 2] = p2;
  sel_boxes[slot * 4 + 3] = p3;
  int lb = plab[idx];
  sel_labels[slot] = lb;
  int m = matches[idx];
  const float* e = gt_ell + ((size_t)b * N_GT + m) * 5;
  float ea = e[0], eb = e[1], ex = e[2], ey = e[3], eth = e[4];
  float w = fmaxf(p2 - p0, 1.0f), h = fmaxf(p3 - p1, 1.0f);
  float cx = 0.5f * (p0 + p2), cy = 0.5f * (p1 + p3);
  float* t = targets + (size_t)slot * 6;
  t[0] = (ex - cx) / w;
  t[1] = (ey - cy) / h;
  t[2] = logf(fmaxf(2.0f * ea, 0.001f) / w);
  t[3] = logf(fmaxf(2.0f * eb, 0.001f) / h);
  t[4] = sinf(2.0f * eth);
  t[5] = cosf(2.0f * eth);
}

// ------------------------------------------------------------- NCHW -> NHWC
__global__ __launch_bounds__(256) void k_transpose(const float* __restrict__ in,
                                                   float* __restrict__ out) {
  __shared__ float tile[32][33];
  int b = blockIdx.z;
  int s0 = blockIdx.x * 32;   // hw
  int c0 = blockIdx.y * 32;   // channel
  int tx = threadIdx.x, ty = threadIdx.y;
  const float* src = in + (size_t)b * C_FEAT * HWF;
  float* dst = out + (size_t)b * HWF * C_FEAT;
#pragma unroll
  for (int yy = ty; yy < 32; yy += 8)
    tile[yy][tx] = src[(size_t)(c0 + yy) * HWF + s0 + tx];
  __syncthreads();
#pragma unroll
  for (int yy = ty; yy < 32; yy += 8)
    dst[(size_t)(s0 + yy) * C_FEAT + c0 + tx] = tile[tx][yy];
}

// ------------------- fast weight cast: fp32 [K][N] -> bf16 [N][K] (64x64 tiles)
// PERM=1: input row = (c0+i)*49+p, output col k = p*256+c  (w1 pooled layout)
// PERM=0: input row = k0+i,        output col k = k0+c     (w2)
// grid PERM=1: (C/64=4, N/64=16, 49);  PERM=0: (K/64, N/64, 1)
template <int PERM>
__global__ __launch_bounds__(256) void k_castT(const float* __restrict__ W,
                                               __hip_bfloat16* __restrict__ WT,
                                               int Kout) {
  __shared__ float t[64][65];
  int p  = blockIdx.z;
  int c0 = blockIdx.x * 64;
  int n0 = blockIdx.y * 64;
  int tx = threadIdx.x & 63, ty = threadIdx.x >> 6;  // 4 row-groups
#pragma unroll
  for (int i = ty; i < 64; i += 4) {
    int krow = PERM ? ((c0 + i) * 49 + p) : (c0 + i);
    t[i][tx] = W[(size_t)krow * HID + n0 + tx];
  }
  __syncthreads();
#pragma unroll
  for (int i = ty; i < 64; i += 4) {
    int kx = PERM ? (p * 256 + c0 + tx) : (c0 + tx);
    WT[(size_t)(n0 + i) * Kout + kx] = __float2bfloat16(t[tx][i]);
  }
}

// ---------------------------------------------------------------- roi align
// block: 256 threads = channels; grid (NSEL, 7=py). X[n][(py*7+px)*256 + c] (bf16)
__global__ __launch_bounds__(256) void k_roialign(const float* __restrict__ featT,
                                                  const float* __restrict__ sel_boxes,
                                                  __hip_bfloat16* __restrict__ X) {
  int n = blockIdx.x;
  int py = blockIdx.y;
  int c = threadIdx.x;
  int b = n >> 9;
  const float* bx = sel_boxes + (size_t)n * 4;
  float x1 = bx[0] * 0.125f, y1 = bx[1] * 0.125f;
  float x2 = bx[2] * 0.125f, y2 = bx[3] * 0.125f;
  float bw = fmaxf(x2 - x1, 1.0f) / 7.0f;
  float bh = fmaxf(y2 - y1, 1.0f) / 7.0f;
  const float* base = featT + (size_t)b * HWF * C_FEAT;
  int y0A[2]; float lyA[2];
#pragma unroll
  for (int sy = 0; sy < 2; sy++) {
    float off = ((float)(py * 2 + sy) + 0.5f) * 0.5f;
    float ys = fminf(fmaxf(y1 + off * bh, 0.0f), 127.0f);
    int y0 = (int)fminf(fmaxf(floorf(ys), 0.0f), 126.0f);
    y0A[sy] = y0; lyA[sy] = ys - (float)y0;
  }
  for (int px = 0; px < 7; px++) {
    float acc = 0.0f;
#pragma unroll
    for (int sx = 0; sx < 2; sx++) {
      float off = ((float)(px * 2 + sx) + 0.5f) * 0.5f;
      float xs = fminf(fmaxf(x1 + off * bw, 0.0f), 127.0f);
      int x0 = (int)fminf(fmaxf(floorf(xs), 0.0f), 126.0f);
      float lx = xs - (float)x0;
#pragma unroll
      for (int sy = 0; sy < 2; sy++) {
        int y0 = y0A[sy]; float ly = lyA[sy];
        const float* p = base + ((size_t)(y0 * W_FEAT + x0)) * C_FEAT + c;
        float v00 = p[0];
        float v01 = p[C_FEAT];
        float v10 = p[W_FEAT * C_FEAT];
        float v11 = p[W_FEAT * C_FEAT + C_FEAT];
        float wy1 = ly, wy0 = 1.0f - ly, wx1 = lx, wx0 = 1.0f - lx;
        acc += v00 * (wy0 * wx0) + v01 * (wy0 * wx1) + v10 * (wy1 * wx0) + v11 * (wy1 * wx1);
      }
    }
    X[(size_t)n * K1 + (size_t)(py * 7 + px) * C_FEAT + c] = __float2bfloat16(acc * 0.25f);
  }
}

// ------------------------------------------------------- bf16 MFMA GEMM (split-K)
// A: M x K bf16 row-major. BT: N x K bf16 row-major. P[z]: 1024x1024 fp32 partials.
// 128x128 tile, BK=32, 4 waves each computing a 64x64 quadrant via 16x16x32 mfma.
__device__ __forceinline__ void gld_lds16(const __hip_bfloat16* g, __hip_bfloat16* l) {
  __builtin_amdgcn_global_load_lds(
      (const __attribute__((address_space(1))) void*)g,
      (__attribute__((address_space(3))) void*)l, 16, 0, 0);
}

__global__ __launch_bounds__(256) void k_mfma_gemm(const __hip_bfloat16* __restrict__ A,
                                                   const __hip_bfloat16* __restrict__ BT,
                                                   float* __restrict__ P,
                                                   int K, int KC) {
  __shared__ __align__(16) __hip_bfloat16 As[128 * 32];
  __shared__ __align__(16) __hip_bfloat16 Bs[128 * 32];
  int tid = threadIdx.x;
  int n0 = blockIdx.x * 128, m0 = blockIdx.y * 128;
  int kz = blockIdx.z;
  int kbeg = kz * KC;
  int srow = tid >> 2;          // 0..63
  int scol = (tid & 3) << 3;    // 0,8,16,24 (elements)
  int wave = tid >> 6, lane = tid & 63;
  int wm = (wave & 1) * 64, wn = (wave >> 1) * 64;
  int lm = lane & 15, quad = lane >> 4;
  f32x4f acc[4][4] = {};
  for (int k0 = kbeg; k0 < kbeg + KC; k0 += 32) {
    __syncthreads();
    gld_lds16(A  + (size_t)(m0 + srow) * K + k0 + scol,      &As[srow * 32 + scol]);
    gld_lds16(A  + (size_t)(m0 + 64 + srow) * K + k0 + scol, &As[(64 + srow) * 32 + scol]);
    gld_lds16(BT + (size_t)(n0 + srow) * K + k0 + scol,      &Bs[srow * 32 + scol]);
    gld_lds16(BT + (size_t)(n0 + 64 + srow) * K + k0 + scol, &Bs[(64 + srow) * 32 + scol]);
    __syncthreads();
    bf16x8f af[4], bf[4];
#pragma unroll
    for (int i = 0; i < 4; i++)
      af[i] = *(const bf16x8f*)&As[(wm + i * 16 + lm) * 32 + quad * 8];
#pragma unroll
    for (int j = 0; j < 4; j++)
      bf[j] = *(const bf16x8f*)&Bs[(wn + j * 16 + lm) * 32 + quad * 8];
#pragma unroll
    for (int i = 0; i < 4; i++)
#pragma unroll
      for (int j = 0; j < 4; j++)
        acc[i][j] = __builtin_amdgcn_mfma_f32_16x16x32_bf16(af[i], bf[j], acc[i][j], 0, 0, 0);
  }
  // C/D layout: col = lane&15, row = quad*4 + reg
#pragma unroll
  for (int i = 0; i < 4; i++)
#pragma unroll
    for (int j = 0; j < 4; j++) {
      float* base = P + ((size_t)kz << 20)
                      + (size_t)(m0 + wm + i * 16 + quad * 4) * HID
                      + (n0 + wn + j * 16 + lm);
#pragma unroll
      for (int r = 0; r < 4; r++) base[(size_t)r * HID] = acc[i][j][r];
    }
}

// reduce split-K partials + bias + relu; OUTBF16 chooses output dtype
template <int Z, int OUTBF16>
__global__ __launch_bounds__(256) void k_reduce(const float* __restrict__ P,
                                                const float* __restrict__ bias,
                                                void* __restrict__ O) {
  int idx4 = blockIdx.x * 256 + threadIdx.x;
  int m = idx4 >> 8;
  int n4 = (idx4 & 255) << 2;
  float4 s = *(const float4*)(bias + n4);
#pragma unroll
  for (int z = 0; z < Z; z++) {
    float4 p = *(const float4*)(P + ((size_t)z << 20) + ((size_t)m << 10) + n4);
    s.x += p.x; s.y += p.y; s.z += p.z; s.w += p.w;
  }
  s.x = fmaxf(s.x, 0.0f); s.y = fmaxf(s.y, 0.0f);
  s.z = fmaxf(s.z, 0.0f); s.w = fmaxf(s.w, 0.0f);
  if (OUTBF16) {
    __hip_bfloat16 t[4] = {__float2bfloat16(s.x), __float2bfloat16(s.y),
                           __float2bfloat16(s.z), __float2bfloat16(s.w)};
    *(short4v*)((__hip_bfloat16*)O + ((size_t)m << 10) + n4) = *(short4v*)t;
  } else {
    *(float4*)((float*)O + ((size_t)m << 10) + n4) = s;
  }
}

// --------------------------------------------------------------- head GEMM
__global__ __launch_bounds__(256) void k_head(const float* __restrict__ H2,
                                              const float* __restrict__ wc,
                                              const float* __restrict__ bc,
                                              const float* __restrict__ wr,
                                              const float* __restrict__ br,
                                              float* __restrict__ Y) {
  __shared__ float Wl[HID * NHEAD];
  int tid = threadIdx.x;
  for (int t = tid; t < HID * NHEAD; t += 256) {
    int k = t / NHEAD, j = t - k * NHEAD;
    Wl[t] = (j < 2) ? wc[k * 2 + j] : wr[k * 12 + (j - 2)];
  }
  __syncthreads();
  int wave = tid >> 6, lane = tid & 63;
  int row = blockIdx.x * 4 + wave;
  float acc[NHEAD];
#pragma unroll
  for (int j = 0; j < NHEAD; j++) acc[j] = 0.0f;
  const float* h = H2 + (size_t)row * HID;
  for (int k = lane; k < HID; k += 64) {
    float hv = h[k];
    const float* wrow = &Wl[k * NHEAD];
#pragma unroll
    for (int j = 0; j < NHEAD; j++) acc[j] = fmaf(hv, wrow[j], acc[j]);
  }
#pragma unroll
  for (int j = 0; j < NHEAD; j++) {
    float v = acc[j];
    for (int off = 32; off > 0; off >>= 1) v += __shfl_down(v, off);
    if (lane == 0) Y[(size_t)row * NHEAD + j] = v + ((j < 2) ? bc[j] : br[j - 2]);
  }
}

// ------------------------------------------------------------------- losses
__global__ __launch_bounds__(1024) void k_loss(const float* __restrict__ Y,
                                               const int* __restrict__ sel_labels,
                                               const float* __restrict__ T,
                                               float* __restrict__ out) {
  __shared__ float sc[1024];
  __shared__ float sr[1024];
  int n = threadIdx.x;
  float l0 = Y[(size_t)n * NHEAD + 0], l1 = Y[(size_t)n * NHEAD + 1];
  int lb = sel_labels[n];
  float mx = fmaxf(l0, l1);
  float lse = mx + logf(expf(l0 - mx) + expf(l1 - mx));
  float ce = lse - (lb ? l1 : l0);
  float reg = 0.0f;
  if (lb > 0) {
    const float beta = 1.0f / 9.0f;
    const float* pr = Y + (size_t)n * NHEAD + 2 + lb * 6;
    const float* t = T + (size_t)n * 6;
#pragma unroll
    for (int j = 0; j < 6; j++) {
      float d = fabsf(pr[j] - t[j]);
      reg += (d < beta) ? (0.5f * d * d / beta) : (d - 0.5f * beta);
    }
  }
  sc[n] = ce; sr[n] = reg;
  __syncthreads();
  for (int s = 512; s > 0; s >>= 1) {
    if (n < s) { sc[n] += sc[n + s]; sr[n] += sr[n + s]; }
    __syncthreads();
  }
  if (n == 0) {
    out[0] = sc[0] * (1.0f / 1024.0f);
    out[1] = sr[0] * (1.0f / 1024.0f);
  }
}

// ------------------------------------------------------------------ launch
extern "C" void kernel_launch(void* const* d_in, const int* in_sizes, int n_in,
                              void* d_out, int out_size, void* d_ws, size_t ws_size,
                              hipStream_t stream) {
  const float* features  = (const float*)d_in[0];
  const float* proposals = (const float*)d_in[1];
  const float* gt_boxes  = (const float*)d_in[2];
  const int*   gt_labels = (const int*)d_in[3];
  const float* gt_ell    = (const float*)d_in[4];
  const float* w1 = (const float*)d_in[5];
  const float* b1 = (const float*)d_in[6];
  const float* w2 = (const float*)d_in[7];
  const float* b2 = (const float*)d_in[8];
  const float* wc = (const float*)d_in[9];
  const float* bc = (const float*)d_in[10];
  const float* wr = (const float*)d_in[11];
  const float* br = (const float*)d_in[12];
  float* out = (float*)d_out;

  char* ws = (char*)d_ws;
  size_t off = 0;
  auto take = [&](size_t bytes) -> void* {
    void* p = ws + off;
    off = (off + bytes + 255) & ~(size_t)255;
    return p;
  };
  // featT (32 MiB, dead after roialign) aliases P (8x4 MiB split-K partials)
  float* featT = (float*)take((size_t)B_IMG * HWF * C_FEAT * 4);       // 32 MiB
  float* P     = featT;                                                // alias
  __hip_bfloat16* Xb  = (__hip_bfloat16*)take((size_t)NSEL * K1 * 2);  // 25.7 MB
  __hip_bfloat16* W1T = (__hip_bfloat16*)take((size_t)HID * K1 * 2);   // 25.7 MB
  __hip_bfloat16* W2T = (__hip_bfloat16*)take((size_t)HID * HID * 2);  // 2.1 MB
  __hip_bfloat16* H1b = (__hip_bfloat16*)take((size_t)NSEL * HID * 2); // 2.1 MB
  float* H2s       = (float*)take((size_t)NSEL * HID * 4);             // 4.2 MB
  float* Y         = (float*)take((size_t)NSEL * NHEAD * 4);
  float* rnd       = (float*)take((size_t)B_IMG * NPROPS * 4);
  int*   matches   = (int*)take((size_t)B_IMG * NPROPS * 4);
  int*   plab      = (int*)take((size_t)B_IMG * NPROPS * 4);
  float* prio      = (float*)take((size_t)B_IMG * NPROPS * 4);
  float* sel_boxes = (float*)take((size_t)NSEL * 4 * 4);
  int*   sel_lab   = (int*)take((size_t)NSEL * 4);
  float* targets   = (float*)take((size_t)NSEL * 6 * 4);

  k_rand<<<(B_IMG * NPROPS + 255) / 256, 256, 0, stream>>>(rnd);
  k_transpose<<<dim3(HWF / 32, C_FEAT / 32, B_IMG), dim3(32, 8), 0, stream>>>(features, featT);
  k_castT<1><<<dim3(C_FEAT / 64, HID / 64, 49), 256, 0, stream>>>(w1, W1T, K1);
  k_castT<0><<<dim3(HID / 64, HID / 64, 1), 256, 0, stream>>>(w2, W2T, HID);
  k_match<<<(B_IMG * NPROPS + 255) / 256, 256, 0, stream>>>(proposals, gt_boxes, gt_labels,
                                                            matches, plab);
  k_prio<<<(B_IMG * NPROPS + 255) / 256, 256, 0, stream>>>(rnd, plab, prio);
  k_select<<<(B_IMG * NPROPS + 255) / 256, 256, 0, stream>>>(prio, proposals, gt_boxes,
                                                             matches, plab, gt_ell,
                                                             sel_boxes, sel_lab, targets);
  k_roialign<<<dim3(NSEL, POOL), 256, 0, stream>>>(featT, sel_boxes, Xb);

  // GEMM1: Xb(1024 x 12544) @ W1T^T, split-K=8 (KC=1568), then reduce+relu -> H1b (bf16)
  k_mfma_gemm<<<dim3(8, 8, 8), 256, 0, stream>>>(Xb, W1T, P, K1, K1 / 8);
  k_reduce<8, 1><<<1024, 256, 0, stream>>>(P, b1, H1b);
  // GEMM2: H1b(1024x1024) @ W2T^T, split-K=4 (KC=256), reduce+relu -> H2 (fp32)
  k_mfma_gemm<<<dim3(8, 8, 4), 256, 0, stream>>>(H1b, W2T, P, HID, HID / 4);
  k_reduce<4, 0><<<1024, 256, 0, stream>>>(P, b2, H2s);

  k_head<<<NSEL / 4, 256, 0, stream>>>(H2s, wc, bc, wr, br, Y);
  k_loss<<<1, 1024, 0, stream>>>(Y, sel_lab, targets, out);
}

// Round 4
// 364.527 us; speedup vs baseline: 2.1169x; 1.2658x over previous
//
#include <hip/hip_runtime.h>
#include <hip/hip_bf16.h>
#include <math.h>

#define B_IMG   2
#define N_PROP  2000
#define N_GT    16
#define NPROPS  2016        // N_PROP + N_GT
#define C_FEAT  256
#define H_FEAT  128
#define W_FEAT  128
#define HWF     (H_FEAT*W_FEAT)
#define POOL    7
#define BPI     512
#define NPOSMAX 128
#define NSEL    (B_IMG*BPI)     // 1024
#define K1      (C_FEAT*POOL*POOL)  // 12544
#define HID     1024
#define NHEAD   14              // 2 logits + 12 reg

typedef short bf16x8f __attribute__((ext_vector_type(8)));   // 8 bf16 = 4 VGPRs
typedef float f32x4f  __attribute__((ext_vector_type(4)));
typedef short short4v __attribute__((ext_vector_type(4)));

// ---------------------------------------------------------------- threefry
__device__ __forceinline__ void threefry2x32(unsigned k0, unsigned k1,
                                             unsigned& x0, unsigned& x1) {
  unsigned ks[3] = {k0, k1, k0 ^ k1 ^ 0x1BD11BDAu};
  const int R0[4] = {13, 15, 26, 6};
  const int R1[4] = {17, 29, 16, 24};
  x0 += ks[0]; x1 += ks[1];
#pragma unroll
  for (int g = 0; g < 5; g++) {
    const int* rot = (g & 1) ? R1 : R0;
#pragma unroll
    for (int r = 0; r < 4; r++) {
      x0 += x1;
      x1 = (x1 << rot[r]) | (x1 >> (32 - rot[r]));
      x1 ^= x0;
    }
    x0 += ks[(g + 1) % 3];
    x1 += ks[(g + 2) % 3] + (unsigned)(g + 1);
  }
}

__global__ void k_rand(float* __restrict__ rnd) {
  int j = blockIdx.x * blockDim.x + threadIdx.x;
  if (j >= B_IMG * NPROPS) return;
  unsigned x0 = 0u, x1 = (unsigned)j;
  threefry2x32(0u, 42u, x0, x1);
  unsigned bits = x0 ^ x1;
  rnd[j] = __uint_as_float((bits >> 9) | 0x3F800000u) - 1.0f;
}

// ---------------------------------------------------------------- matching
__global__ void k_match(const float* __restrict__ proposals,
                        const float* __restrict__ gt_boxes,
                        const int* __restrict__ gt_labels,
                        int* __restrict__ matches, int* __restrict__ plab) {
  int idx = blockIdx.x * blockDim.x + threadIdx.x;
  if (idx >= B_IMG * NPROPS) return;
  int b = idx / NPROPS, i = idx - b * NPROPS;
  float p0, p1, p2, p3;
  if (i < N_PROP) {
    const float* p = proposals + ((size_t)b * N_PROP + i) * 4;
    p0 = p[0]; p1 = p[1]; p2 = p[2]; p3 = p[3];
  } else {
    const float* p = gt_boxes + ((size_t)b * N_GT + (i - N_PROP)) * 4;
    p0 = p[0]; p1 = p[1]; p2 = p[2]; p3 = p[3];
  }
  float a2 = (p2 - p0) * (p3 - p1);
  float best = -1.0f; int bg = 0;
  for (int g = 0; g < N_GT; g++) {
    const float* gb = gt_boxes + ((size_t)b * N_GT + g) * 4;
    float g0 = gb[0], g1 = gb[1], g2 = gb[2], g3 = gb[3];
    float a1 = (g2 - g0) * (g3 - g1);
    float wx = fminf(g2, p2) - fmaxf(g0, p0);
    float wy = fminf(g3, p3) - fmaxf(g1, p1);
    wx = fmaxf(wx, 0.0f); wy = fmaxf(wy, 0.0f);
    float inter = wx * wy;
    float iou = inter / (a1 + a2 - inter);
    if (iou > best) { best = iou; bg = g; }
  }
  matches[idx] = bg;
  plab[idx] = (best < 0.5f) ? 0 : gt_labels[b * N_GT + bg];
}

// ---------------------------------------------------------------- priorities
// one block per image. Compact positives, then rank only among positives.
// Positive rank semantics = stable argsort of (-rand, index): rank(i) =
// #{j pos: rj>ri or (rj==ri and j<i)}. Negatives (-1e9 in pos_s) never
// outrank positives since rand >= 0.
__global__ __launch_bounds__(256) void k_prio(const float* __restrict__ rnd,
                                              const int* __restrict__ plab,
                                              float* __restrict__ prio) {
  __shared__ float rs[NPROPS];
  __shared__ int   pos_i[NPROPS];
  __shared__ float pos_r[NPROPS];
  __shared__ int   cnt;
  int tid = threadIdx.x;
  int base = blockIdx.x * NPROPS;
  if (tid == 0) cnt = 0;
  __syncthreads();
  for (int t = tid; t < NPROPS; t += 256) {
    float r = rnd[base + t];
    int l = plab[base + t];
    rs[t] = r;
    if (l > 0) {
      int s = atomicAdd(&cnt, 1);
      pos_i[s] = t; pos_r[s] = r;
    } else {
      prio[base + t] = r;      // negative: prio = rand
    }
  }
  __syncthreads();
  int P = cnt;
  for (int s = tid; s < P; s += 256) {
    int i = pos_i[s];
    float ri = pos_r[s];
    int ch = 0;
    for (int j = 0; j < P; j++) {
      float rj = pos_r[j];
      int ij = pos_i[j];
      ch += (rj > ri || (rj == ri && ij < i)) ? 1 : 0;
    }
    prio[base + i] = (ch < NPOSMAX) ? (ri + 2.0f) : -1000000000.0f;
  }
}

// ------------------------------------------------- select + gather + encode
__global__ __launch_bounds__(256) void k_select(const float* __restrict__ prio,
    const float* __restrict__ proposals, const float* __restrict__ gt_boxes,
    const int* __restrict__ matches, const int* __restrict__ plab,
    const float* __restrict__ gt_ell,
    float* __restrict__ sel_boxes, int* __restrict__ sel_labels,
    float* __restrict__ targets) {
  __shared__ float ps[B_IMG * NPROPS];
  int tid = threadIdx.x;
  for (int t = tid; t < B_IMG * NPROPS; t += 256) ps[t] = prio[t];
  __syncthreads();
  int idx = blockIdx.x * 256 + tid;
  if (idx >= B_IMG * NPROPS) return;
  int b = idx / NPROPS, i = idx - b * NPROPS;
  int base = b * NPROPS;
  float pi = ps[idx];
  int rank = 0;
#pragma unroll 8
  for (int j = 0; j < NPROPS; j++) {
    float pj = ps[base + j];
    rank += (pj > pi || (pj == pi && j < i)) ? 1 : 0;
  }
  if (rank >= BPI) return;
  int slot = b * BPI + rank;
  float p0, p1, p2, p3;
  if (i < N_PROP) {
    const float* p = proposals + ((size_t)b * N_PROP + i) * 4;
    p0 = p[0]; p1 = p[1]; p2 = p[2]; p3 = p[3];
  } else {
    const float* p = gt_boxes + ((size_t)b * N_GT + (i - N_PROP)) * 4;
    p0 = p[0]; p1 = p[1]; p2 = p[2]; p3 = p[3];
  }
  sel_boxes[slot * 4 + 0] = p0;
  sel_boxes[slot * 4 + 1] = p1;
  sel_boxes[slot * 4 + 2] = p2;
  sel_boxes[slot * 4 + 3] = p3;
  int lb = plab[idx];
  sel_labels[slot] = lb;
  int m = matches[idx];
  const float* e = gt_ell + ((size_t)b * N_GT + m) * 5;
  float ea = e[0], eb = e[1], ex = e[2], ey = e[3], eth = e[4];
  float w = fmaxf(p2 - p0, 1.0f), h = fmaxf(p3 - p1, 1.0f);
  float cx = 0.5f * (p0 + p2), cy = 0.5f * (p1 + p3);
  float* t = targets + (size_t)slot * 6;
  t[0] = (ex - cx) / w;
  t[1] = (ey - cy) / h;
  t[2] = logf(fmaxf(2.0f * ea, 0.001f) / w);
  t[3] = logf(fmaxf(2.0f * eb, 0.001f) / h);
  t[4] = sinf(2.0f * eth);
  t[5] = cosf(2.0f * eth);
}

// ------------------------------------------------------------- NCHW -> NHWC
__global__ __launch_bounds__(256) void k_transpose(const float* __restrict__ in,
                                                   float* __restrict__ out) {
  __shared__ float tile[32][33];
  int b = blockIdx.z;
  int s0 = blockIdx.x * 32;   // hw
  int c0 = blockIdx.y * 32;   // channel
  int tx = threadIdx.x, ty = threadIdx.y;
  const float* src = in + (size_t)b * C_FEAT * HWF;
  float* dst = out + (size_t)b * HWF * C_FEAT;
#pragma unroll
  for (int yy = ty; yy < 32; yy += 8)
    tile[yy][tx] = src[(size_t)(c0 + yy) * HWF + s0 + tx];
  __syncthreads();
#pragma unroll
  for (int yy = ty; yy < 32; yy += 8)
    dst[(size_t)(s0 + yy) * C_FEAT + c0 + tx] = tile[tx][yy];
}

// ------------------- fast weight cast: fp32 [K][N] -> bf16 [N][K] (64x64 tiles)
// PERM=1: input row = (c0+i)*49+p, output col k = p*256+c  (w1 pooled layout)
// PERM=0: input row = k0+i,        output col k = k0+c     (w2)
// grid PERM=1: (C/64=4, N/64=16, 49);  PERM=0: (K/64, N/64, 1)
template <int PERM>
__global__ __launch_bounds__(256) void k_castT(const float* __restrict__ W,
                                               __hip_bfloat16* __restrict__ WT,
                                               int Kout) {
  __shared__ float t[64][65];
  int p  = blockIdx.z;
  int c0 = blockIdx.x * 64;
  int n0 = blockIdx.y * 64;
  int tx = threadIdx.x & 63, ty = threadIdx.x >> 6;  // 4 row-groups
#pragma unroll
  for (int i = ty; i < 64; i += 4) {
    int krow = PERM ? ((c0 + i) * 49 + p) : (c0 + i);
    t[i][tx] = W[(size_t)krow * HID + n0 + tx];
  }
  __syncthreads();
#pragma unroll
  for (int i = ty; i < 64; i += 4) {
    int kx = PERM ? (p * 256 + c0 + tx) : (c0 + tx);
    WT[(size_t)(n0 + i) * Kout + kx] = __float2bfloat16(t[tx][i]);
  }
}

// ---------------------------------------------------------------- roi align
// block: 256 threads = channels; grid (NSEL, 7=py). X[n][(py*7+px)*256 + c] (bf16)
__global__ __launch_bounds__(256) void k_roialign(const float* __restrict__ featT,
                                                  const float* __restrict__ sel_boxes,
                                                  __hip_bfloat16* __restrict__ X) {
  int n = blockIdx.x;
  int py = blockIdx.y;
  int c = threadIdx.x;
  int b = n >> 9;
  const float* bx = sel_boxes + (size_t)n * 4;
  float x1 = bx[0] * 0.125f, y1 = bx[1] * 0.125f;
  float x2 = bx[2] * 0.125f, y2 = bx[3] * 0.125f;
  float bw = fmaxf(x2 - x1, 1.0f) / 7.0f;
  float bh = fmaxf(y2 - y1, 1.0f) / 7.0f;
  const float* base = featT + (size_t)b * HWF * C_FEAT;
  int y0A[2]; float lyA[2];
#pragma unroll
  for (int sy = 0; sy < 2; sy++) {
    float off = ((float)(py * 2 + sy) + 0.5f) * 0.5f;
    float ys = fminf(fmaxf(y1 + off * bh, 0.0f), 127.0f);
    int y0 = (int)fminf(fmaxf(floorf(ys), 0.0f), 126.0f);
    y0A[sy] = y0; lyA[sy] = ys - (float)y0;
  }
  for (int px = 0; px < 7; px++) {
    float acc = 0.0f;
#pragma unroll
    for (int sx = 0; sx < 2; sx++) {
      float off = ((float)(px * 2 + sx) + 0.5f) * 0.5f;
      float xs = fminf(fmaxf(x1 + off * bw, 0.0f), 127.0f);
      int x0 = (int)fminf(fmaxf(floorf(xs), 0.0f), 126.0f);
      float lx = xs - (float)x0;
#pragma unroll
      for (int sy = 0; sy < 2; sy++) {
        int y0 = y0A[sy]; float ly = lyA[sy];
        const float* p = base + ((size_t)(y0 * W_FEAT + x0)) * C_FEAT + c;
        float v00 = p[0];
        float v01 = p[C_FEAT];
        float v10 = p[W_FEAT * C_FEAT];
        float v11 = p[W_FEAT * C_FEAT + C_FEAT];
        float wy1 = ly, wy0 = 1.0f - ly, wx1 = lx, wx0 = 1.0f - lx;
        acc += v00 * (wy0 * wx0) + v01 * (wy0 * wx1) + v10 * (wy1 * wx0) + v11 * (wy1 * wx1);
      }
    }
    X[(size_t)n * K1 + (size_t)(py * 7 + px) * C_FEAT + c] = __float2bfloat16(acc * 0.25f);
  }
}

// ------------------------------------------------------- bf16 MFMA GEMM (split-K)
// A: M x K bf16 row-major. BT: N x K bf16 row-major. P[z]: 1024x1024 fp32 partials.
// 128x128 tile, BK=32, 4 waves each computing a 64x64 quadrant via 16x16x32 mfma.
__device__ __forceinline__ void gld_lds16(const __hip_bfloat16* g, __hip_bfloat16* l) {
  __builtin_amdgcn_global_load_lds(
      (const __attribute__((address_space(1))) void*)g,
      (__attribute__((address_space(3))) void*)l, 16, 0, 0);
}

__global__ __launch_bounds__(256) void k_mfma_gemm(const __hip_bfloat16* __restrict__ A,
                                                   const __hip_bfloat16* __restrict__ BT,
                                                   float* __restrict__ P,
                                                   int K, int KC) {
  __shared__ __align__(16) __hip_bfloat16 As[128 * 32];
  __shared__ __align__(16) __hip_bfloat16 Bs[128 * 32];
  int tid = threadIdx.x;
  int n0 = blockIdx.x * 128, m0 = blockIdx.y * 128;
  int kz = blockIdx.z;
  int kbeg = kz * KC;
  int srow = tid >> 2;          // 0..63
  int scol = (tid & 3) << 3;    // 0,8,16,24 (elements)
  int wave = tid >> 6, lane = tid & 63;
  int wm = (wave & 1) * 64, wn = (wave >> 1) * 64;
  int lm = lane & 15, quad = lane >> 4;
  f32x4f acc[4][4] = {};
  for (int k0 = kbeg; k0 < kbeg + KC; k0 += 32) {
    __syncthreads();
    gld_lds16(A  + (size_t)(m0 + srow) * K + k0 + scol,      &As[srow * 32 + scol]);
    gld_lds16(A  + (size_t)(m0 + 64 + srow) * K + k0 + scol, &As[(64 + srow) * 32 + scol]);
    gld_lds16(BT + (size_t)(n0 + srow) * K + k0 + scol,      &Bs[srow * 32 + scol]);
    gld_lds16(BT + (size_t)(n0 + 64 + srow) * K + k0 + scol, &Bs[(64 + srow) * 32 + scol]);
    __syncthreads();
    bf16x8f af[4], bf[4];
#pragma unroll
    for (int i = 0; i < 4; i++)
      af[i] = *(const bf16x8f*)&As[(wm + i * 16 + lm) * 32 + quad * 8];
#pragma unroll
    for (int j = 0; j < 4; j++)
      bf[j] = *(const bf16x8f*)&Bs[(wn + j * 16 + lm) * 32 + quad * 8];
#pragma unroll
    for (int i = 0; i < 4; i++)
#pragma unroll
      for (int j = 0; j < 4; j++)
        acc[i][j] = __builtin_amdgcn_mfma_f32_16x16x32_bf16(af[i], bf[j], acc[i][j], 0, 0, 0);
  }
  // C/D layout: col = lane&15, row = quad*4 + reg
#pragma unroll
  for (int i = 0; i < 4; i++)
#pragma unroll
    for (int j = 0; j < 4; j++) {
      float* base = P + ((size_t)kz << 20)
                      + (size_t)(m0 + wm + i * 16 + quad * 4) * HID
                      + (n0 + wn + j * 16 + lm);
#pragma unroll
      for (int r = 0; r < 4; r++) base[(size_t)r * HID] = acc[i][j][r];
    }
}

// reduce split-K partials + bias + relu; OUTBF16 chooses output dtype
template <int Z, int OUTBF16>
__global__ __launch_bounds__(256) void k_reduce(const float* __restrict__ P,
                                                const float* __restrict__ bias,
                                                void* __restrict__ O) {
  int idx4 = blockIdx.x * 256 + threadIdx.x;
  int m = idx4 >> 8;
  int n4 = (idx4 & 255) << 2;
  float4 s = *(const float4*)(bias + n4);
#pragma unroll
  for (int z = 0; z < Z; z++) {
    float4 p = *(const float4*)(P + ((size_t)z << 20) + ((size_t)m << 10) + n4);
    s.x += p.x; s.y += p.y; s.z += p.z; s.w += p.w;
  }
  s.x = fmaxf(s.x, 0.0f); s.y = fmaxf(s.y, 0.0f);
  s.z = fmaxf(s.z, 0.0f); s.w = fmaxf(s.w, 0.0f);
  if (OUTBF16) {
    __hip_bfloat16 t[4] = {__float2bfloat16(s.x), __float2bfloat16(s.y),
                           __float2bfloat16(s.z), __float2bfloat16(s.w)};
    *(short4v*)((__hip_bfloat16*)O + ((size_t)m << 10) + n4) = *(short4v*)t;
  } else {
    *(float4*)((float*)O + ((size_t)m << 10) + n4) = s;
  }
}

// --------------------------------------------------------------- head GEMM
__global__ __launch_bounds__(256) void k_head(const float* __restrict__ H2,
                                              const float* __restrict__ wc,
                                              const float* __restrict__ bc,
                                              const float* __restrict__ wr,
                                              const float* __restrict__ br,
                                              float* __restrict__ Y) {
  __shared__ float Wl[HID * NHEAD];
  int tid = threadIdx.x;
  for (int t = tid; t < HID * NHEAD; t += 256) {
    int k = t / NHEAD, j = t - k * NHEAD;
    Wl[t] = (j < 2) ? wc[k * 2 + j] : wr[k * 12 + (j - 2)];
  }
  __syncthreads();
  int wave = tid >> 6, lane = tid & 63;
  int row = blockIdx.x * 4 + wave;
  float acc[NHEAD];
#pragma unroll
  for (int j = 0; j < NHEAD; j++) acc[j] = 0.0f;
  const float* h = H2 + (size_t)row * HID;
  for (int k = lane; k < HID; k += 64) {
    float hv = h[k];
    const float* wrow = &Wl[k * NHEAD];
#pragma unroll
    for (int j = 0; j < NHEAD; j++) acc[j] = fmaf(hv, wrow[j], acc[j]);
  }
#pragma unroll
  for (int j = 0; j < NHEAD; j++) {
    float v = acc[j];
    for (int off = 32; off > 0; off >>= 1) v += __shfl_down(v, off);
    if (lane == 0) Y[(size_t)row * NHEAD + j] = v + ((j < 2) ? bc[j] : br[j - 2]);
  }
}

// ------------------------------------------------------------------- losses
__global__ __launch_bounds__(1024) void k_loss(const float* __restrict__ Y,
                                               const int* __restrict__ sel_labels,
                                               const float* __restrict__ T,
                                               float* __restrict__ out) {
  __shared__ float sc[1024];
  __shared__ float sr[1024];
  int n = threadIdx.x;
  float l0 = Y[(size_t)n * NHEAD + 0], l1 = Y[(size_t)n * NHEAD + 1];
  int lb = sel_labels[n];
  float mx = fmaxf(l0, l1);
  float lse = mx + logf(expf(l0 - mx) + expf(l1 - mx));
  float ce = lse - (lb ? l1 : l0);
  float reg = 0.0f;
  if (lb > 0) {
    const float beta = 1.0f / 9.0f;
    const float* pr = Y + (size_t)n * NHEAD + 2 + lb * 6;
    const float* t = T + (size_t)n * 6;
#pragma unroll
    for (int j = 0; j < 6; j++) {
      float d = fabsf(pr[j] - t[j]);
      reg += (d < beta) ? (0.5f * d * d / beta) : (d - 0.5f * beta);
    }
  }
  sc[n] = ce; sr[n] = reg;
  __syncthreads();
  for (int s = 512; s > 0; s >>= 1) {
    if (n < s) { sc[n] += sc[n + s]; sr[n] += sr[n + s]; }
    __syncthreads();
  }
  if (n == 0) {
    out[0] = sc[0] * (1.0f / 1024.0f);
    out[1] = sr[0] * (1.0f / 1024.0f);
  }
}

// ------------------------------------------------------------------ launch
extern "C" void kernel_launch(void* const* d_in, const int* in_sizes, int n_in,
                              void* d_out, int out_size, void* d_ws, size_t ws_size,
                              hipStream_t stream) {
  const float* features  = (const float*)d_in[0];
  const float* proposals = (const float*)d_in[1];
  const float* gt_boxes  = (const float*)d_in[2];
  const int*   gt_labels = (const int*)d_in[3];
  const float* gt_ell    = (const float*)d_in[4];
  const float* w1 = (const float*)d_in[5];
  const float* b1 = (const float*)d_in[6];
  const float* w2 = (const float*)d_in[7];
  const float* b2 = (const float*)d_in[8];
  const float* wc = (const float*)d_in[9];
  const float* bc = (const float*)d_in[10];
  const float* wr = (const float*)d_in[11];
  const float* br = (const float*)d_in[12];
  float* out = (float*)d_out;

  char* ws = (char*)d_ws;
  size_t off = 0;
  auto take = [&](size_t bytes) -> void* {
    void* p = ws + off;
    off = (off + bytes + 255) & ~(size_t)255;
    return p;
  };
  // featT (32 MiB, dead after roialign) aliases P (8x4 MiB split-K partials)
  float* featT = (float*)take((size_t)B_IMG * HWF * C_FEAT * 4);       // 32 MiB
  float* P     = featT;                                                // alias
  __hip_bfloat16* Xb  = (__hip_bfloat16*)take((size_t)NSEL * K1 * 2);  // 25.7 MB
  __hip_bfloat16* W1T = (__hip_bfloat16*)take((size_t)HID * K1 * 2);   // 25.7 MB
  __hip_bfloat16* W2T = (__hip_bfloat16*)take((size_t)HID * HID * 2);  // 2.1 MB
  __hip_bfloat16* H1b = (__hip_bfloat16*)take((size_t)NSEL * HID * 2); // 2.1 MB
  float* H2s       = (float*)take((size_t)NSEL * HID * 4);             // 4.2 MB
  float* Y         = (float*)take((size_t)NSEL * NHEAD * 4);
  float* rnd       = (float*)take((size_t)B_IMG * NPROPS * 4);
  int*   matches   = (int*)take((size_t)B_IMG * NPROPS * 4);
  int*   plab      = (int*)take((size_t)B_IMG * NPROPS * 4);
  float* prio      = (float*)take((size_t)B_IMG * NPROPS * 4);
  float* sel_boxes = (float*)take((size_t)NSEL * 4 * 4);
  int*   sel_lab   = (int*)take((size_t)NSEL * 4);
  float* targets   = (float*)take((size_t)NSEL * 6 * 4);

  k_rand<<<(B_IMG * NPROPS + 255) / 256, 256, 0, stream>>>(rnd);
  k_transpose<<<dim3(HWF / 32, C_FEAT / 32, B_IMG), dim3(32, 8), 0, stream>>>(features, featT);
  k_castT<1><<<dim3(C_FEAT / 64, HID / 64, 49), 256, 0, stream>>>(w1, W1T, K1);
  k_castT<0><<<dim3(HID / 64, HID / 64, 1), 256, 0, stream>>>(w2, W2T, HID);
  k_match<<<(B_IMG * NPROPS + 255) / 256, 256, 0, stream>>>(proposals, gt_boxes, gt_labels,
                                                            matches, plab);
  k_prio<<<B_IMG, 256, 0, stream>>>(rnd, plab, prio);
  k_select<<<(B_IMG * NPROPS + 255) / 256, 256, 0, stream>>>(prio, proposals, gt_boxes,
                                                             matches, plab, gt_ell,
                                                             sel_boxes, sel_lab, targets);
  k_roialign<<<dim3(NSEL, POOL), 256, 0, stream>>>(featT, sel_boxes, Xb);

  // GEMM1: Xb(1024 x 12544) @ W1T^T, split-K=8 (KC=1568), then reduce+relu -> H1b (bf16)
  k_mfma_gemm<<<dim3(8, 8, 8), 256, 0, stream>>>(Xb, W1T, P, K1, K1 / 8);
  k_reduce<8, 1><<<1024, 256, 0, stream>>>(P, b1, H1b);
  // GEMM2: H1b(1024x1024) @ W2T^T, split-K=4 (KC=256), reduce+relu -> H2 (fp32)
  k_mfma_gemm<<<dim3(8, 8, 4), 256, 0, stream>>>(H1b, W2T, P, HID, HID / 4);
  k_reduce<4, 0><<<1024, 256, 0, stream>>>(P, b2, H2s);

  k_head<<<NSEL / 4, 256, 0, stream>>>(H2s, wc, bc, wr, br, Y);
  k_loss<<<1, 1024, 0, stream>>>(Y, sel_lab, targets, out);
}